// Round 5
// baseline (283.661 us; speedup 1.0000x reference)
//
#include <hip/hip_runtime.h>
#include <hip/hip_bf16.h>

// Fused: out[m,:] = relu( (softmax_n(relu([pus|pis|pss]@W1+b1)@W2+b2) .
//                          relu([C|pss]@WR+bR)) @ Wo + bo )
// One block per m, 512 threads (8 waves, 2x4 wave grid, 64x32 out/wave).
// 10 K-steps of 64. X: f32->bf16 reg-staged into XOR-swizzled LDS (dbuf,
// depth-2 prefetch). W: B-fragments loaded global->VGPR per step (L2-resident,
// no LDS, no manual vmcnt). Sync: lgkmcnt(0) + raw s_barrier per step only.

#define M_ 4096
#define N_ 100
#define E_ 128

typedef __bf16 bf16x8 __attribute__((ext_vector_type(8)));
typedef float  f32x4  __attribute__((ext_vector_type(4)));

// W1t[n][k] = bf16(W1[k][n]) (n<128,k<384); WRt[n][k] = bf16(WR[k][n]) (k<256)
__global__ void prep_weights(const float* __restrict__ W1, const float* __restrict__ WR,
                             __bf16* __restrict__ W1t, __bf16* __restrict__ WRt) {
    int i = blockIdx.x * 256 + threadIdx.x;
    if (i < 384 * 128) {
        int n = i / 384, k = i % 384;
        W1t[i] = (__bf16)W1[k * 128 + n];
    } else {
        int j = i - 384 * 128;
        if (j < 256 * 128) {
            int n = j / 256, k = j % 256;
            WRt[j] = (__bf16)WR[k * 128 + n];
        }
    }
}

__global__ __launch_bounds__(512, 4) void fused(
    const float* __restrict__ pus, const float* __restrict__ pis,
    const float* __restrict__ pss, const float* __restrict__ Cc,
    const __bf16* __restrict__ W1t, const float* __restrict__ b1,
    const float* __restrict__ W2, const float* __restrict__ b2,
    const __bf16* __restrict__ WRt, const float* __restrict__ bR,
    const float* __restrict__ Wo, const float* __restrict__ bo,
    float* __restrict__ out)
{
    __shared__ __align__(16) __bf16 Xs[2][128][64];
    __shared__ float part[4][128];
    __shared__ float sLDS[128];
    __shared__ float wLDS[128];
    __shared__ float pairLDS[128];

    const int tid  = threadIdx.x;
    const int lane = tid & 63;
    const int wid  = tid >> 6;          // 0..7
    const int wr = wid >> 2, wc = wid & 3;   // 2 x 4 wave grid
    const int g  = lane >> 4;           // k-group 0..3
    const int m = blockIdx.x;
    const long base = (long)m * (N_ * E_);

    // hoisted small operands (cols per wave: wc*32 + b*16 + lane15, b<2)
    float w2v[2], b1v[2], bRv[2];
    #pragma unroll
    for (int b = 0; b < 2; ++b) {
        int col = wc * 32 + b * 16 + (lane & 15);
        w2v[b] = W2[col]; b1v[b] = b1[col]; bRv[b] = bR[col];
    }
    const float b2v = b2[0];

    float4 xvE[4], xvO[4];

    // X fetch for step `step`: 4 float4/thread; pad rows clamp to row 99
    // (masked later: softmax mask / weight=0).
    auto fetchX = [&](float4 (&xv)[4], int step) {
        const float* __restrict__ src =
            (step < 2) ? pus : (step < 4) ? pis : (step < 6) ? pss
          : (step < 8) ? Cc : pss;
        const int colbase = (step & 1) << 6;
        #pragma unroll
        for (int i = 0; i < 4; ++i) {
            int c  = tid + 512 * i;
            int r  = c >> 4;
            int rc = (r < N_) ? r : (N_ - 1);
            int k4 = (c & 15) << 2;
            xv[i] = *reinterpret_cast<const float4*>(
                src + base + (long)rc * E_ + colbase + k4);
        }
    };
    // cvt f32->bf16 + XOR-swizzled ds_write into buffer `buf`
    auto writeX = [&](float4 (&xv)[4], int buf) {
        #pragma unroll
        for (int i = 0; i < 4; ++i) {
            int c  = tid + 512 * i;
            int r  = c >> 4;
            int k4 = (c & 15) << 2;
            int blk  = k4 >> 3;
            int phys = ((blk ^ (r & 7)) << 3) + (k4 & 7);
            union { __bf16 h[4]; uint2 u; } tw;
            tw.h[0] = (__bf16)xv[i].x; tw.h[1] = (__bf16)xv[i].y;
            tw.h[2] = (__bf16)xv[i].z; tw.h[3] = (__bf16)xv[i].w;
            *reinterpret_cast<uint2*>(&Xs[buf][r][phys]) = tw.u;
        }
    };

    f32x4 acc[4][2] = {};

    // ---- prologue ----
    fetchX(xvE, 0);
    fetchX(xvO, 1);
    writeX(xvE, 0);            // compiler waits xvE loads
    fetchX(xvE, 2);
    asm volatile("s_waitcnt lgkmcnt(0)" ::: "memory");
    __builtin_amdgcn_s_barrier();
    __builtin_amdgcn_sched_barrier(0);

    #pragma unroll
    for (int s = 0; s < 10; ++s) {
        const int cur = s & 1;

        // W B-fragments for this step: global->VGPR (L2-resident weights)
        const __bf16* __restrict__ Wt = (s < 6) ? W1t : WRt;
        const int wstride = (s < 6) ? 384 : 256;
        const int k0 = (s < 6) ? s * 64 : (s - 6) * 64;
        bf16x8 wf[2][2];
        #pragma unroll
        for (int ks = 0; ks < 2; ++ks) {
            const int kblk = (ks << 2) + g;
            #pragma unroll
            for (int b = 0; b < 2; ++b) {
                int nn = wc * 32 + b * 16 + (lane & 15);
                wf[ks][b] = *reinterpret_cast<const bf16x8*>(
                    Wt + nn * wstride + k0 + (kblk << 3));
            }
        }

        // stage next X tile, prefetch X(s+3)
        if (s < 9) {
            if (((s + 1) & 1) == 0) {
                writeX(xvE, cur ^ 1);
                if (s + 3 < 10) fetchX(xvE, s + 3);
            } else {
                writeX(xvO, cur ^ 1);
                if (s + 3 < 10) fetchX(xvO, s + 3);
            }
        }

        // MFMA cluster on Xs[cur] + wf
        #pragma unroll
        for (int ks = 0; ks < 2; ++ks) {
            const int kblk = (ks << 2) + g;
            bf16x8 af[4];
            #pragma unroll
            for (int a = 0; a < 4; ++a) {
                int rr = wr * 64 + a * 16 + (lane & 15);
                af[a] = *reinterpret_cast<const bf16x8*>(
                    &Xs[cur][rr][(kblk ^ (rr & 7)) << 3]);
            }
            #pragma unroll
            for (int a = 0; a < 4; ++a)
                #pragma unroll
                for (int b = 0; b < 2; ++b)
                    acc[a][b] = __builtin_amdgcn_mfma_f32_16x16x32_bf16(
                        af[a], wf[ks][b], acc[a][b], 0, 0, 0);
        }

        if (s == 5) {
            // ---- epilogue A: scores + softmax ----
            #pragma unroll
            for (int a = 0; a < 4; ++a) {
                #pragma unroll
                for (int r = 0; r < 4; ++r) {
                    float ps = 0.f;
                    #pragma unroll
                    for (int b = 0; b < 2; ++b) {
                        float h = fmaxf(acc[a][b][r] + b1v[b], 0.f);
                        ps += h * w2v[b];
                    }
                    ps += __shfl_xor(ps, 1);
                    ps += __shfl_xor(ps, 2);
                    ps += __shfl_xor(ps, 4);
                    ps += __shfl_xor(ps, 8);
                    if ((lane & 15) == 0) {
                        int row = wr * 64 + a * 16 + g * 4 + r;
                        part[wc][row] = ps;
                    }
                }
            }
            asm volatile("s_waitcnt lgkmcnt(0)" ::: "memory");
            __builtin_amdgcn_s_barrier();
            __builtin_amdgcn_sched_barrier(0);
            if (tid < 128)
                sLDS[tid] = part[0][tid] + part[1][tid] + part[2][tid]
                          + part[3][tid] + b2v;
            asm volatile("s_waitcnt lgkmcnt(0)" ::: "memory");
            __builtin_amdgcn_s_barrier();
            __builtin_amdgcn_sched_barrier(0);
            if (wid == 0) {
                float s0 = (lane < N_) ? sLDS[lane] : -3e38f;
                float s1 = (lane + 64 < N_) ? sLDS[lane + 64] : -3e38f;
                float mx = fmaxf(s0, s1);
                #pragma unroll
                for (int off = 1; off < 64; off <<= 1) mx = fmaxf(mx, __shfl_xor(mx, off));
                float e0 = (lane < N_) ? __expf(s0 - mx) : 0.f;
                float e1 = (lane + 64 < N_) ? __expf(s1 - mx) : 0.f;
                float sum = e0 + e1;
                #pragma unroll
                for (int off = 1; off < 64; off <<= 1) sum += __shfl_xor(sum, off);
                float inv = 1.f / sum;
                wLDS[lane]      = e0 * inv;
                wLDS[lane + 64] = e1 * inv;
            }
            // wLDS visible via the remaining loop-end barriers (steps 5..9)
            #pragma unroll
            for (int a = 0; a < 4; ++a)
                #pragma unroll
                for (int b = 0; b < 2; ++b)
                    #pragma unroll
                    for (int q = 0; q < 4; ++q)
                        acc[a][b][q] = 0.f;
        }

        asm volatile("s_waitcnt lgkmcnt(0)" ::: "memory");
        __builtin_amdgcn_s_barrier();
        __builtin_amdgcn_sched_barrier(0);
    }

    // ---- epilogue B: weighted pooling + lout ----
    {
        float psum[2] = {0.f, 0.f};
        #pragma unroll
        for (int a = 0; a < 4; ++a) {
            #pragma unroll
            for (int r = 0; r < 4; ++r) {
                int row = wr * 64 + a * 16 + g * 4 + r;
                float wgt = wLDS[row];
                #pragma unroll
                for (int b = 0; b < 2; ++b) {
                    float v = fmaxf(acc[a][b][r] + bRv[b], 0.f);
                    psum[b] += wgt * v;
                }
            }
        }
        #pragma unroll
        for (int b = 0; b < 2; ++b) {
            psum[b] += __shfl_xor(psum[b], 16);
            psum[b] += __shfl_xor(psum[b], 32);
        }
        if (lane < 16) {
            #pragma unroll
            for (int b = 0; b < 2; ++b)
                part[wr][wc * 32 + b * 16 + lane] = psum[b];
        }
        __syncthreads();
        if (tid < 128) pairLDS[tid] = part[0][tid] + part[1][tid];
        __syncthreads();
        if (tid < 128) {
            float o = bo[tid];
            #pragma unroll 8
            for (int k = 0; k < 128; ++k)
                o += pairLDS[k] * Wo[k * 128 + tid];
            out[(long)m * 128 + tid] = fmaxf(o, 0.f);
        }
    }
}

extern "C" void kernel_launch(void* const* d_in, const int* in_sizes, int n_in,
                              void* d_out, int out_size, void* d_ws, size_t ws_size,
                              hipStream_t stream) {
    const float* pus = (const float*)d_in[2];
    const float* pis = (const float*)d_in[3];
    const float* pss = (const float*)d_in[4];
    const float* C   = (const float*)d_in[5];
    const float* W1  = (const float*)d_in[6];
    const float* b1  = (const float*)d_in[7];
    const float* W2  = (const float*)d_in[8];
    const float* b2  = (const float*)d_in[9];
    const float* WR  = (const float*)d_in[10];
    const float* bR  = (const float*)d_in[11];
    const float* Wo  = (const float*)d_in[12];
    const float* bo  = (const float*)d_in[13];
    (void)in_sizes; (void)n_in; (void)ws_size;

    // workspace: W1t bf16[128*384] | WRt bf16[128*256]
    __bf16* W1t = (__bf16*)d_ws;
    __bf16* WRt = W1t + 384 * 128;

    prep_weights<<<320, 256, 0, stream>>>(W1, WR, W1t, WRt);
    fused<<<M_, 512, 0, stream>>>(pus, pis, pss, C, W1t, b1, W2, b2,
                                  WRt, bR, Wo, bo, (float*)d_out);
}

// Round 6
// 283.349 us; speedup vs baseline: 1.0011x; 1.0011x over previous
//
#include <hip/hip_runtime.h>
#include <hip/hip_bf16.h>

// Fused: out[m,:] = relu( (softmax_n(relu([pus|pis|pss]@W1+b1)@W2+b2) .
//                          relu([C|pss]@WR+bR)) @ Wo + bo )
// One block per m, 512 threads (8 waves, 2x4 grid, 64x32 out/wave), 10 K-steps
// of 64. R6 = R4 pipeline (W async via global_load_lds dbuf, X f32->bf16
// reg-staged dbuf, depth-2 prefetch, counted vmcnt) + R5 geometry (acc 32 regs,
// 8 waves) for 2x the resident waves of R4.

#define M_ 4096
#define N_ 100
#define E_ 128

typedef __bf16 bf16x8 __attribute__((ext_vector_type(8)));
typedef float  f32x4  __attribute__((ext_vector_type(4)));

#define GLOAD_LDS16(g, l)                                                    \
  __builtin_amdgcn_global_load_lds(                                          \
      (const __attribute__((address_space(1))) void*)(g),                    \
      (__attribute__((address_space(3))) void*)(l), 16, 0, 0)

// W1t[n][k] = bf16(W1[k][n]) (n<128,k<384); WRt[n][k] = bf16(WR[k][n]) (k<256)
__global__ void prep_weights(const float* __restrict__ W1, const float* __restrict__ WR,
                             __bf16* __restrict__ W1t, __bf16* __restrict__ WRt) {
    int i = blockIdx.x * 256 + threadIdx.x;
    if (i < 384 * 128) {
        int n = i / 384, k = i % 384;
        W1t[i] = (__bf16)W1[k * 128 + n];
    } else {
        int j = i - 384 * 128;
        if (j < 256 * 128) {
            int n = j / 256, k = j % 256;
            WRt[j] = (__bf16)WR[k * 128 + n];
        }
    }
}

__global__ __launch_bounds__(512, 3) void fused(
    const float* __restrict__ pus, const float* __restrict__ pis,
    const float* __restrict__ pss, const float* __restrict__ Cc,
    const __bf16* __restrict__ W1t, const float* __restrict__ b1,
    const float* __restrict__ W2, const float* __restrict__ b2,
    const __bf16* __restrict__ WRt, const float* __restrict__ bR,
    const float* __restrict__ Wo, const float* __restrict__ bo,
    float* __restrict__ out)
{
    __shared__ __align__(16) __bf16 Xs[2][128][64];
    __shared__ __align__(16) __bf16 Ws[2][128][64];
    __shared__ float part[4][128];
    __shared__ float sLDS[128];
    __shared__ float wLDS[128];
    __shared__ float pairLDS[128];

    const int tid  = threadIdx.x;
    const int lane = tid & 63;
    const int wid  = tid >> 6;               // 0..7
    const int wr = wid >> 2, wc = wid & 3;   // 2 x 4 wave grid
    const int g  = lane >> 4;                // k-group 0..3
    const int m = blockIdx.x;
    const long base = (long)m * (N_ * E_);

    // hoisted small operands (keeps main-loop vmcnt queue clean)
    float w2v[2], b1v[2], bRv[2];
    #pragma unroll
    for (int b = 0; b < 2; ++b) {
        int col = wc * 32 + b * 16 + (lane & 15);
        w2v[b] = W2[col]; b1v[b] = b1[col]; bRv[b] = bR[col];
    }
    const float b2v = b2[0];

    float4 xvE[4], xvO[4];

    // X fetch for step `step`: 4 float4/thread; pad rows clamp to row 99
    // (masked later: softmax mask / weight=0).
    auto fetchX = [&](float4 (&xv)[4], int step) {
        const float* __restrict__ src =
            (step < 2) ? pus : (step < 4) ? pis : (step < 6) ? pss
          : (step < 8) ? Cc : pss;
        const int colbase = (step & 1) << 6;
        #pragma unroll
        for (int i = 0; i < 4; ++i) {
            int c  = tid + 512 * i;
            int r  = c >> 4;
            int rc = (r < N_) ? r : (N_ - 1);
            int k4 = (c & 15) << 2;
            xv[i] = *reinterpret_cast<const float4*>(
                src + base + (long)rc * E_ + colbase + k4);
        }
    };
    // cvt f32->bf16 + XOR-swizzled ds_write into buffer `buf`
    auto writeX = [&](float4 (&xv)[4], int buf) {
        #pragma unroll
        for (int i = 0; i < 4; ++i) {
            int c  = tid + 512 * i;
            int r  = c >> 4;
            int k4 = (c & 15) << 2;
            int blk  = k4 >> 3;
            int phys = ((blk ^ (r & 7)) << 3) + (k4 & 7);
            union { __bf16 h[4]; uint2 u; } tw;
            tw.h[0] = (__bf16)xv[i].x; tw.h[1] = (__bf16)xv[i].y;
            tw.h[2] = (__bf16)xv[i].z; tw.h[3] = (__bf16)xv[i].w;
            *reinterpret_cast<uint2*>(&Xs[buf][r][phys]) = tw.u;
        }
    };
    // W stage: linear LDS dest, inverse-swizzled global source (rule 21);
    // 16 x 1KB segments over 8 waves x 2.
    auto stageW = [&](int step, int buf) {
        const __bf16* __restrict__ Wt = (step < 6) ? W1t : WRt;
        const int wstride = (step < 6) ? 384 : 256;
        const int k0 = (step < 6) ? step * 64 : (step - 6) * 64;
        #pragma unroll
        for (int j = 0; j < 2; ++j) {
            int seg = wid * 2 + j;
            int n  = seg * 8 + (lane >> 3);
            int kb = (lane & 7) ^ (n & 7);
            GLOAD_LDS16(Wt + n * wstride + k0 + (kb << 3), &Ws[buf][seg * 8][0]);
        }
    };

    f32x4 acc[4][2] = {};

    // ---- prologue: buf0 filled, X(1) in regs, X(2) in flight ----
    fetchX(xvE, 0);
    fetchX(xvO, 1);
    stageW(0, 0);
    __builtin_amdgcn_sched_barrier(0);
    writeX(xvE, 0);            // compiler waits the xvE loads
    fetchX(xvE, 2);
    __builtin_amdgcn_sched_barrier(0);
    asm volatile("s_waitcnt lgkmcnt(0)" ::: "memory");
    asm volatile("s_waitcnt vmcnt(4)" ::: "memory");   // drains xvO+W(0); X(2) in flight
    __builtin_amdgcn_s_barrier();
    __builtin_amdgcn_sched_barrier(0);

    #pragma unroll
    for (int s = 0; s < 10; ++s) {
        const int cur = s & 1;

        // issue next-step memory first; MFMA hides its latency
        if (s < 9) {
            stageW(s + 1, cur ^ 1);
            __builtin_amdgcn_sched_barrier(0);   // pin W-before-X issue order
            if (((s + 1) & 1) == 0) {
                writeX(xvE, cur ^ 1);
                if (s + 3 < 10) fetchX(xvE, s + 3);
            } else {
                writeX(xvO, cur ^ 1);
                if (s + 3 < 10) fetchX(xvO, s + 3);
            }
            __builtin_amdgcn_sched_barrier(0);
        }

        // MFMA cluster on buffers `cur`
        __builtin_amdgcn_s_setprio(1);
        #pragma unroll
        for (int ks = 0; ks < 2; ++ks) {
            const int kblk = (ks << 2) + g;
            bf16x8 af[4], wf[2];
            #pragma unroll
            for (int a = 0; a < 4; ++a) {
                int rr = wr * 64 + a * 16 + (lane & 15);
                af[a] = *reinterpret_cast<const bf16x8*>(
                    &Xs[cur][rr][(kblk ^ (rr & 7)) << 3]);
            }
            #pragma unroll
            for (int b = 0; b < 2; ++b) {
                int nn = wc * 32 + b * 16 + (lane & 15);
                wf[b] = *reinterpret_cast<const bf16x8*>(
                    &Ws[cur][nn][(kblk ^ (nn & 7)) << 3]);
            }
            #pragma unroll
            for (int a = 0; a < 4; ++a)
                #pragma unroll
                for (int b = 0; b < 2; ++b)
                    acc[a][b] = __builtin_amdgcn_mfma_f32_16x16x32_bf16(
                        af[a], wf[b], acc[a][b], 0, 0, 0);
        }
        __builtin_amdgcn_s_setprio(0);

        if (s == 5) {
            // ---- epilogue A: scores + softmax (raw barriers: no vmcnt drain) ----
            #pragma unroll
            for (int a = 0; a < 4; ++a) {
                #pragma unroll
                for (int r = 0; r < 4; ++r) {
                    float ps = 0.f;
                    #pragma unroll
                    for (int b = 0; b < 2; ++b) {
                        float h = fmaxf(acc[a][b][r] + b1v[b], 0.f);
                        ps += h * w2v[b];
                    }
                    ps += __shfl_xor(ps, 1);
                    ps += __shfl_xor(ps, 2);
                    ps += __shfl_xor(ps, 4);
                    ps += __shfl_xor(ps, 8);
                    if ((lane & 15) == 0) {
                        int row = wr * 64 + a * 16 + g * 4 + r;
                        part[wc][row] = ps;
                    }
                }
            }
            asm volatile("s_waitcnt lgkmcnt(0)" ::: "memory");
            __builtin_amdgcn_s_barrier();
            __builtin_amdgcn_sched_barrier(0);
            if (tid < 128)
                sLDS[tid] = part[0][tid] + part[1][tid] + part[2][tid]
                          + part[3][tid] + b2v;
            asm volatile("s_waitcnt lgkmcnt(0)" ::: "memory");
            __builtin_amdgcn_s_barrier();
            __builtin_amdgcn_sched_barrier(0);
            if (wid == 0) {
                float s0 = (lane < N_) ? sLDS[lane] : -3e38f;
                float s1 = (lane + 64 < N_) ? sLDS[lane + 64] : -3e38f;
                float mx = fmaxf(s0, s1);
                #pragma unroll
                for (int off = 1; off < 64; off <<= 1) mx = fmaxf(mx, __shfl_xor(mx, off));
                float e0 = (lane < N_) ? __expf(s0 - mx) : 0.f;
                float e1 = (lane + 64 < N_) ? __expf(s1 - mx) : 0.f;
                float sum = e0 + e1;
                #pragma unroll
                for (int off = 1; off < 64; off <<= 1) sum += __shfl_xor(sum, off);
                float inv = 1.f / sum;
                wLDS[lane]      = e0 * inv;
                wLDS[lane + 64] = e1 * inv;
            }
            // wLDS visible via the remaining loop-end lgkm(0)+barriers
            #pragma unroll
            for (int a = 0; a < 4; ++a)
                #pragma unroll
                for (int b = 0; b < 2; ++b)
                    #pragma unroll
                    for (int q = 0; q < 4; ++q)
                        acc[a][b][q] = 0.f;
        }

        asm volatile("s_waitcnt lgkmcnt(0)" ::: "memory");
        if (s < 7) asm volatile("s_waitcnt vmcnt(4)" ::: "memory");  // W+X(s+2) done, X(s+3) in flight
        else       asm volatile("s_waitcnt vmcnt(0)" ::: "memory");  // tail
        __builtin_amdgcn_s_barrier();
        __builtin_amdgcn_sched_barrier(0);
    }

    // ---- epilogue B: weighted pooling + lout ----
    {
        float psum[2] = {0.f, 0.f};
        #pragma unroll
        for (int a = 0; a < 4; ++a) {
            #pragma unroll
            for (int r = 0; r < 4; ++r) {
                int row = wr * 64 + a * 16 + g * 4 + r;
                float wgt = wLDS[row];
                #pragma unroll
                for (int b = 0; b < 2; ++b) {
                    float v = fmaxf(acc[a][b][r] + bRv[b], 0.f);
                    psum[b] += wgt * v;
                }
            }
        }
        #pragma unroll
        for (int b = 0; b < 2; ++b) {
            psum[b] += __shfl_xor(psum[b], 16);
            psum[b] += __shfl_xor(psum[b], 32);
        }
        if (lane < 16) {
            #pragma unroll
            for (int b = 0; b < 2; ++b)
                part[wr][wc * 32 + b * 16 + lane] = psum[b];
        }
        __syncthreads();
        if (tid < 128) pairLDS[tid] = part[0][tid] + part[1][tid];
        __syncthreads();
        if (tid < 128) {
            float o = bo[tid];
            #pragma unroll 8
            for (int k = 0; k < 128; ++k)
                o += pairLDS[k] * Wo[k * 128 + tid];
            out[(long)m * 128 + tid] = fmaxf(o, 0.f);
        }
    }
}

extern "C" void kernel_launch(void* const* d_in, const int* in_sizes, int n_in,
                              void* d_out, int out_size, void* d_ws, size_t ws_size,
                              hipStream_t stream) {
    const float* pus = (const float*)d_in[2];
    const float* pis = (const float*)d_in[3];
    const float* pss = (const float*)d_in[4];
    const float* C   = (const float*)d_in[5];
    const float* W1  = (const float*)d_in[6];
    const float* b1  = (const float*)d_in[7];
    const float* W2  = (const float*)d_in[8];
    const float* b2  = (const float*)d_in[9];
    const float* WR  = (const float*)d_in[10];
    const float* bR  = (const float*)d_in[11];
    const float* Wo  = (const float*)d_in[12];
    const float* bo  = (const float*)d_in[13];
    (void)in_sizes; (void)n_in; (void)ws_size;

    // workspace: W1t bf16[128*384] | WRt bf16[128*256]
    __bf16* W1t = (__bf16*)d_ws;
    __bf16* WRt = W1t + 384 * 128;

    prep_weights<<<320, 256, 0, stream>>>(W1, WR, W1t, WRt);
    fused<<<M_, 512, 0, stream>>>(pus, pis, pss, C, W1t, b1, W2, b2,
                                  WRt, bR, Wo, bo, (float*)d_out);
}